// Round 5
// baseline (228.808 us; speedup 1.0000x reference)
//
#include <hip/hip_runtime.h>

typedef float f32x4 __attribute__((ext_vector_type(4)));
typedef __bf16 bf16x8 __attribute__((ext_vector_type(8)));
typedef unsigned short u16x4 __attribute__((ext_vector_type(4)));

__device__ __forceinline__ unsigned short f2bf(float f) {
  union { float f; unsigned int u; } v; v.f = f;
  unsigned int r = (v.u + 0x7FFFu + ((v.u >> 16) & 1u)) >> 16;
  return (unsigned short)r;
}
__device__ __forceinline__ float bf2f(unsigned short h) {
  union { unsigned int u; float f; } v; v.u = ((unsigned int)h) << 16;
  return v.f;
}
__device__ __forceinline__ void gload_lds16(const void* g, void* l) {
  __builtin_amdgcn_global_load_lds(
      (const __attribute__((address_space(1))) unsigned int*)g,
      (__attribute__((address_space(3))) unsigned int*)l, 16, 0, 0);
}

// ---------------- prep: fp32->bf16 casts (all 3 arrays) + RoPE cos/sin table
__global__ __launch_bounds__(256) void prep_kernel(
    const float* __restrict__ x, const float* __restrict__ wqkv,
    const float* __restrict__ wout, unsigned short* __restrict__ xb,
    unsigned short* __restrict__ wqkvb, unsigned short* __restrict__ woutb,
    float2* __restrict__ tab) {
  const int N1 = 1048576, N2 = 786432, N3 = 262144;  // float4 counts
  int idx = blockIdx.x * 256 + threadIdx.x;
  if (idx < N1 + N2 + N3) {
    const float* src; unsigned short* dst; int i = idx;
    if (i < N1)           { src = x;    dst = xb; }
    else if (i < N1 + N2) { i -= N1;      src = wqkv; dst = wqkvb; }
    else                  { i -= N1 + N2; src = wout; dst = woutb; }
    float4 v = ((const float4*)src)[i];
    u16x4 o;
    o.x = f2bf(v.x); o.y = f2bf(v.y); o.z = f2bf(v.z); o.w = f2bf(v.w);
    ((u16x4*)dst)[i] = o;
  } else {
    int i = idx - (N1 + N2 + N3);
    if (i < 65536) {  // 2048 positions x 32 pairs
      int t = i >> 5, p = i & 31;
      float theta = exp2f(-(float)p * 0.4152410118609203f);  // log2(1e4)/32
      float sn, cs;
      sincosf((float)t * theta, &sn, &cs);
      tab[i] = make_float2(cs, sn);
    }
  }
}

// ---------------- GEMM1: qkv = x * Wqkv^T, m97 structure, RoPE epilogue ----
// 128x128 tile, BK=32, 256 thr / 4 waves, each wave 64x64 (4x4 16x16 frags).
__global__ __launch_bounds__(256) void gemm1_rope(
    const unsigned short* __restrict__ A,   // x bf16 [4096][1024]
    const unsigned short* __restrict__ B,   // Wqkv bf16 [3072][1024]
    unsigned short* __restrict__ Cq,        // qkv bf16 [4096][3072]
    const float2* __restrict__ tab) {
  __shared__ unsigned short As[128][32];
  __shared__ unsigned short Bs[128][32];
  const int K = 1024, NJ = 3072;
  const int tid = threadIdx.x;
  const int lane = tid & 63;
  const int w = tid >> 6, wr = w >> 1, wc = w & 1;
  const int bm = blockIdx.y * 128, bn = blockIdx.x * 128;
  const int t4 = tid >> 2, c8 = (tid & 3) * 8;
  const unsigned short* Ab = A + (size_t)(bm + t4) * K + c8;
  const unsigned short* Bb = B + (size_t)(bn + t4) * K + c8;
  const int rq = lane & 15, hi = lane >> 4, kg = hi * 8;
  f32x4 acc[4][4] = {};
  for (int kt = 0; kt < K; kt += 32) {
    gload_lds16(Ab + kt,                  &As[t4][c8]);
    gload_lds16(Ab + kt + (size_t)64 * K, &As[t4 + 64][c8]);
    gload_lds16(Bb + kt,                  &Bs[t4][c8]);
    gload_lds16(Bb + kt + (size_t)64 * K, &Bs[t4 + 64][c8]);
    __syncthreads();
    bf16x8 fa[4], fb[4];
#pragma unroll
    for (int m = 0; m < 4; ++m) fa[m] = *(const bf16x8*)&As[wr * 64 + m * 16 + rq][kg];
#pragma unroll
    for (int n = 0; n < 4; ++n) fb[n] = *(const bf16x8*)&Bs[wc * 64 + n * 16 + rq][kg];
#pragma unroll
    for (int m = 0; m < 4; ++m)
#pragma unroll
      for (int n = 0; n < 4; ++n)
        acc[m][n] = __builtin_amdgcn_mfma_f32_16x16x32_bf16(fa[m], fb[n], acc[m][n], 0, 0, 0);
    __syncthreads();
  }
  // epilogue: RoPE on q,k column sections, then bf16 store
  const int r0 = bm + wr * 64 + hi * 4;
  const int c0 = bn + wc * 64 + rq;
#pragma unroll
  for (int m = 0; m < 4; ++m)
#pragma unroll
    for (int n = 0; n < 4; ++n) {
      int col = c0 + n * 16;
      int cw = col % 192;            // within-head: q<64, k<128, v>=128
      bool dorot = cw < 128;
      int p = (cw & 63) >> 1;
#pragma unroll
      for (int j = 0; j < 4; ++j) {
        int row = r0 + m * 16 + j;
        float val = acc[m][n][j];
        float part = __shfl_xor(val, 1);   // pair partner (adjacent column)
        float outv = val;
        if (dorot) {
          float2 cssn = tab[(row & 2047) * 32 + p];
          outv = (col & 1) ? (part * cssn.y + val * cssn.x)
                           : (val * cssn.x - part * cssn.y);
        }
        Cq[(size_t)row * NJ + col] = f2bf(outv);
      }
    }
}

// ---------------- bf16 GEMM, C = A * B^T (out-proj, fp32 out) --------------
__global__ __launch_bounds__(256) void gemm_bt_f32(const unsigned short* __restrict__ A,
                                                   const unsigned short* __restrict__ B,
                                                   float* __restrict__ C,
                                                   int M, int N, int K) {
  __shared__ unsigned short As[128][32];
  __shared__ unsigned short Bs[128][32];
  const int tid = threadIdx.x;
  const int lane = tid & 63;
  const int w = tid >> 6, wr = w >> 1, wc = w & 1;
  const int bm = blockIdx.y * 128, bn = blockIdx.x * 128;
  const int t4 = tid >> 2, c8 = (tid & 3) * 8;
  const unsigned short* Ab = A + (size_t)(bm + t4) * K + c8;
  const unsigned short* Bb = B + (size_t)(bn + t4) * K + c8;
  const int rq = lane & 15, kg = (lane >> 4) * 8;
  f32x4 acc[4][4] = {};
  for (int kt = 0; kt < K; kt += 32) {
    gload_lds16(Ab + kt,                  &As[t4][c8]);
    gload_lds16(Ab + kt + (size_t)64 * K, &As[t4 + 64][c8]);
    gload_lds16(Bb + kt,                  &Bs[t4][c8]);
    gload_lds16(Bb + kt + (size_t)64 * K, &Bs[t4 + 64][c8]);
    __syncthreads();
    bf16x8 fa[4], fb[4];
#pragma unroll
    for (int m = 0; m < 4; ++m) fa[m] = *(const bf16x8*)&As[wr * 64 + m * 16 + rq][kg];
#pragma unroll
    for (int n = 0; n < 4; ++n) fb[n] = *(const bf16x8*)&Bs[wc * 64 + n * 16 + rq][kg];
#pragma unroll
    for (int m = 0; m < 4; ++m)
#pragma unroll
      for (int n = 0; n < 4; ++n)
        acc[m][n] = __builtin_amdgcn_mfma_f32_16x16x32_bf16(fa[m], fb[n], acc[m][n], 0, 0, 0);
    __syncthreads();
  }
  const int r0 = bm + wr * 64 + (lane >> 4) * 4;
  const int c0 = bn + wc * 64 + rq;
#pragma unroll
  for (int m = 0; m < 4; ++m)
#pragma unroll
    for (int n = 0; n < 4; ++n)
#pragma unroll
      for (int j = 0; j < 4; ++j)
        C[(size_t)(r0 + m * 16 + j) * N + c0 + n * 16] = acc[m][n][j];
}

// ---------------- sliding-window attention ---------------------------------
// One 256-thread block per (b, h, 64-row q-tile). Keys slot s=0..319 map to
// j = qbase-256+s (clamped for staging; masked in scores).
// Vt column index is XOR-swizzled with (d>>4)&3 (bits 4..5) so the V-transpose
// scatter's four tc-groups land on four distinct 32B bank windows (8-way -> 2-way).
#define WMAX 256
__global__ __launch_bounds__(256) void attn_kernel(const unsigned short* __restrict__ qkv,
                                                   unsigned short* __restrict__ attnb,
                                                   const int* __restrict__ winp) {
  __shared__ unsigned short Qs[64][72];
  __shared__ unsigned short KPs[320 * 72];   // K tile; later aliased as P[64][328]
  __shared__ unsigned short Vt[64][328];     // V^T, column-swizzled
  const int T = 2048;
  const int tid = threadIdx.x;
  const int bid = blockIdx.x;
  const int qt = bid & 31;
  const int bh = bid >> 5;
  const int b = bh >> 4, h = bh & 15;
  const int qbase = qt * 64;
  const int kbase = qbase - WMAX;
  const int win = *winp;
  const unsigned short* base = qkv + (size_t)b * T * 3072 + h * 192;
  const int tr = tid >> 2, tc = (tid & 3) * 16;
  const int vswz = (tid & 3) << 4;           // (d>>4)&3 for d = tc..tc+15
  {
    const unsigned short* s = base + (size_t)(qbase + tr) * 3072 + tc;
    *(int4*)&Qs[tr][tc]     = *(const int4*)s;
    *(int4*)&Qs[tr][tc + 8] = *(const int4*)(s + 8);
  }
#pragma unroll
  for (int p5 = 0; p5 < 5; ++p5) {
    int s = p5 * 64 + tr;
    int j = kbase + s;
    int jc = j < 0 ? 0 : j;
    const unsigned short* sk = base + (size_t)jc * 3072 + 64 + tc;
    *(int4*)&KPs[s * 72 + tc]     = *(const int4*)sk;
    *(int4*)&KPs[s * 72 + tc + 8] = *(const int4*)(sk + 8);
    const unsigned short* sv = base + (size_t)jc * 3072 + 128 + tc;
    unsigned short tmp[16];
    *(int4*)&tmp[0] = *(const int4*)sv;
    *(int4*)&tmp[8] = *(const int4*)(sv + 8);
    int ssw = s ^ vswz;
#pragma unroll
    for (int e = 0; e < 16; ++e) Vt[tc + e][ssw] = tmp[e];
  }
  __syncthreads();
  const int lane = tid & 63, wv = tid >> 6;
  const int rbase = wv * 16;
  const int rq = lane & 15, kg = (lane >> 4) * 8;
  bf16x8 qa[2];
#pragma unroll
  for (int kk = 0; kk < 2; ++kk)
    qa[kk] = *(const bf16x8*)&Qs[rbase + rq][kk * 32 + kg];
  float sc[20][4];
#pragma unroll
  for (int n = 0; n < 20; ++n) {
    // wave-uniform skip of fully-masked 16-column blocks
    int jlo = kbase + n * 16;
    if (jlo + 15 >= 0 && jlo <= qbase + rbase + 15) {
      f32x4 s = {};
#pragma unroll
      for (int kk = 0; kk < 2; ++kk) {
        bf16x8 kb = *(const bf16x8*)&KPs[(n * 16 + rq) * 72 + kk * 32 + kg];
        s = __builtin_amdgcn_mfma_f32_16x16x32_bf16(qa[kk], kb, s, 0, 0, 0);
      }
#pragma unroll
      for (int r = 0; r < 4; ++r) sc[n][r] = s[r];
    } else {
#pragma unroll
      for (int r = 0; r < 4; ++r) sc[n][r] = -1e30f;
    }
  }
  const float scale = 0.125f;  // 1/sqrt(64)
#pragma unroll
  for (int r = 0; r < 4; ++r) {
    const int i = qbase + rbase + (lane >> 4) * 4 + r;
    float mx = -1e30f;
#pragma unroll
    for (int n = 0; n < 20; ++n) {
      int j = kbase + n * 16 + rq;
      bool valid = (j >= 0) && (j <= i) && (i - j <= win);
      float v = valid ? sc[n][r] * scale : -1e30f;
      sc[n][r] = v;
      mx = fmaxf(mx, v);
    }
#pragma unroll
    for (int off = 1; off < 16; off <<= 1) mx = fmaxf(mx, __shfl_xor(mx, off));
    float sum = 0.f;
#pragma unroll
    for (int n = 0; n < 20; ++n) {
      float pv = __expf(sc[n][r] - mx);
      sc[n][r] = pv;
      sum += pv;
    }
#pragma unroll
    for (int off = 1; off < 16; off <<= 1) sum += __shfl_xor(sum, off);
    float inv = 1.0f / sum;
#pragma unroll
    for (int n = 0; n < 20; ++n) sc[n][r] *= inv;
  }
  __syncthreads();  // all K reads done before KPs is reused as P
#pragma unroll
  for (int n = 0; n < 20; ++n)
#pragma unroll
    for (int r = 0; r < 4; ++r)
      KPs[(rbase + (lane >> 4) * 4 + r) * 328 + n * 16 + rq] = f2bf(sc[n][r]);
  // PV: O(16x64) = P(16x320) * V(320x64), per wave; Vt reads un-swizzle
  f32x4 oacc[4] = {};
#pragma unroll
  for (int kk = 0; kk < 10; ++kk) {
    bf16x8 pa = *(const bf16x8*)&KPs[(rbase + rq) * 328 + kk * 32 + kg];
#pragma unroll
    for (int n = 0; n < 4; ++n) {
      bf16x8 vb = *(const bf16x8*)&Vt[n * 16 + rq][(kk * 32 + kg) ^ (n << 4)];
      oacc[n] = __builtin_amdgcn_mfma_f32_16x16x32_bf16(pa, vb, oacc[n], 0, 0, 0);
    }
  }
#pragma unroll
  for (int n = 0; n < 4; ++n)
#pragma unroll
    for (int j = 0; j < 4; ++j) {
      int r = qbase + rbase + (lane >> 4) * 4 + j;
      int d = n * 16 + rq;
      attnb[(size_t)(b * T + r) * 1024 + h * 64 + d] = f2bf(oacc[n][j]);
    }
}

// ---------------- launch ----------------------------------------------------
extern "C" void kernel_launch(void* const* d_in, const int* in_sizes, int n_in,
                              void* d_out, int out_size, void* d_ws, size_t ws_size,
                              hipStream_t stream) {
  const float* x    = (const float*)d_in[0];
  const float* Wqkv = (const float*)d_in[1];
  const float* Wout = (const float*)d_in[2];
  const int*   winp = (const int*)d_in[3];

  const int M = 4096, C = 1024, N1 = 3072;
  unsigned short* xb    = (unsigned short*)d_ws;
  unsigned short* wqkvb = xb    + (size_t)M * C;
  unsigned short* woutb = wqkvb + (size_t)N1 * C;
  unsigned short* qkvb  = woutb + (size_t)C * C;
  unsigned short* attnb = qkvb  + (size_t)M * N1;
  float2*         tab   = (float2*)(attnb + (size_t)M * C);  // 2048*32 float2

  const int PREP = 1048576 + 786432 + 262144 + 65536;
  prep_kernel<<<(PREP + 255) / 256, 256, 0, stream>>>(x, Wqkv, Wout, xb, wqkvb,
                                                      woutb, tab);

  gemm1_rope<<<dim3(N1 / 128, M / 128), 256, 0, stream>>>(xb, wqkvb, qkvb, tab);

  attn_kernel<<<2 * 16 * 32, 256, 0, stream>>>(qkvb, attnb, winp);

  gemm_bt_f32<<<dim3(C / 128, M / 128), 256, 0, stream>>>(attnb, woutb,
                                                          (float*)d_out, M, C, C);
}

// Round 9
// 193.936 us; speedup vs baseline: 1.1798x; 1.1798x over previous
//
#include <hip/hip_runtime.h>

typedef float f32x4 __attribute__((ext_vector_type(4)));
typedef __bf16 bf16x8 __attribute__((ext_vector_type(8)));
typedef unsigned short u16x4 __attribute__((ext_vector_type(4)));

__device__ __forceinline__ unsigned short f2bf(float f) {
  union { float f; unsigned int u; } v; v.f = f;
  unsigned int r = (v.u + 0x7FFFu + ((v.u >> 16) & 1u)) >> 16;
  return (unsigned short)r;
}
__device__ __forceinline__ float bf2f(unsigned short h) {
  union { unsigned int u; float f; } v; v.u = ((unsigned int)h) << 16;
  return v.f;
}
__device__ __forceinline__ void gload_lds16(const void* g, void* l) {
  __builtin_amdgcn_global_load_lds(
      (const __attribute__((address_space(1))) unsigned int*)g,
      (__attribute__((address_space(3))) unsigned int*)l, 16, 0, 0);
}

// ---------------- prep: fp32->bf16 casts (all 3 arrays) + RoPE cos/sin table
__global__ __launch_bounds__(256) void prep_kernel(
    const float* __restrict__ x, const float* __restrict__ wqkv,
    const float* __restrict__ wout, unsigned short* __restrict__ xb,
    unsigned short* __restrict__ wqkvb, unsigned short* __restrict__ woutb,
    float2* __restrict__ tab) {
  const int N1 = 1048576, N2 = 786432, N3 = 262144;  // float4 counts
  int idx = blockIdx.x * 256 + threadIdx.x;
  if (idx < N1 + N2 + N3) {
    const float* src; unsigned short* dst; int i = idx;
    if (i < N1)           { src = x;    dst = xb; }
    else if (i < N1 + N2) { i -= N1;      src = wqkv; dst = wqkvb; }
    else                  { i -= N1 + N2; src = wout; dst = woutb; }
    float4 v = ((const float4*)src)[i];
    u16x4 o;
    o.x = f2bf(v.x); o.y = f2bf(v.y); o.z = f2bf(v.z); o.w = f2bf(v.w);
    ((u16x4*)dst)[i] = o;
  } else {
    int i = idx - (N1 + N2 + N3);
    if (i < 65536) {  // 2048 positions x 32 pairs
      int t = i >> 5, p = i & 31;
      float theta = exp2f(-(float)p * 0.4152410118609203f);  // log2(1e4)/32
      float sn, cs;
      sincosf((float)t * theta, &sn, &cs);
      tab[i] = make_float2(cs, sn);
    }
  }
}

// ---------------- bf16 GEMM, C = A * B^T  (A: MxK, B: NxK, both K-major) ----
// 128x128 tile, BK=32, 4 waves each computing 64x64 (4x4 frags of 16x16).
// EXACT round-3 structure (43.3us measured) — runtime M,N,K, no epilogue fusion.
template <bool OUTBF16>
__global__ __launch_bounds__(256) void gemm_bt(const unsigned short* __restrict__ A,
                                               const unsigned short* __restrict__ B,
                                               void* __restrict__ C,
                                               int M, int N, int K) {
  __shared__ unsigned short As[128][32];
  __shared__ unsigned short Bs[128][32];
  const int tid = threadIdx.x;
  const int lane = tid & 63;
  const int w = tid >> 6, wr = w >> 1, wc = w & 1;
  const int bm = blockIdx.y * 128, bn = blockIdx.x * 128;
  const int t4 = tid >> 2, c8 = (tid & 3) * 8;
  const unsigned short* Ab = A + (size_t)(bm + t4) * K + c8;
  const unsigned short* Bb = B + (size_t)(bn + t4) * K + c8;
  const int rq = lane & 15, kg = (lane >> 4) * 8;
  f32x4 acc[4][4] = {};
  for (int kt = 0; kt < K; kt += 32) {
    gload_lds16(Ab + kt,                  &As[t4][c8]);
    gload_lds16(Ab + kt + (size_t)64 * K, &As[t4 + 64][c8]);
    gload_lds16(Bb + kt,                  &Bs[t4][c8]);
    gload_lds16(Bb + kt + (size_t)64 * K, &Bs[t4 + 64][c8]);
    __syncthreads();
    bf16x8 fa[4], fb[4];
#pragma unroll
    for (int m = 0; m < 4; ++m) fa[m] = *(const bf16x8*)&As[wr * 64 + m * 16 + rq][kg];
#pragma unroll
    for (int n = 0; n < 4; ++n) fb[n] = *(const bf16x8*)&Bs[wc * 64 + n * 16 + rq][kg];
#pragma unroll
    for (int m = 0; m < 4; ++m)
#pragma unroll
      for (int n = 0; n < 4; ++n)
        acc[m][n] = __builtin_amdgcn_mfma_f32_16x16x32_bf16(fa[m], fb[n], acc[m][n], 0, 0, 0);
    __syncthreads();
  }
  const int r0 = bm + wr * 64 + (lane >> 4) * 4;
  const int c0 = bn + wc * 64 + rq;
#pragma unroll
  for (int m = 0; m < 4; ++m)
#pragma unroll
    for (int n = 0; n < 4; ++n)
#pragma unroll
      for (int j = 0; j < 4; ++j) {
        int row = r0 + m * 16 + j, col = c0 + n * 16;
        if (OUTBF16)
          ((unsigned short*)C)[(size_t)row * N + col] = f2bf(acc[m][n][j]);
        else
          ((float*)C)[(size_t)row * N + col] = acc[m][n][j];
      }
}

// ---------------- sliding-window attention with RoPE-on-stage --------------
// One 256-thread block per (b, h, 64-row q-tile). Keys slot s=0..319 map to
// j = qbase-256+s (clamped for staging; masked in scores). Q and K are
// rotated (RoPE) during reg-staging using the precomputed cos/sin table.
// Vt column index is XOR-swizzled with (d>>4)&3 so the V-transpose scatter's
// four tc-groups land on distinct 32B bank windows.
#define WMAX 256

__device__ __forceinline__ void rope16(unsigned short* e, const float2* __restrict__ tb) {
#pragma unroll
  for (int p = 0; p < 8; ++p) {
    float2 cs = tb[p];
    float a = bf2f(e[2 * p]), b = bf2f(e[2 * p + 1]);
    e[2 * p]     = f2bf(a * cs.x - b * cs.y);
    e[2 * p + 1] = f2bf(a * cs.y + b * cs.x);
  }
}

__global__ __launch_bounds__(256) void attn_kernel(const unsigned short* __restrict__ qkv,
                                                   unsigned short* __restrict__ attnb,
                                                   const int* __restrict__ winp,
                                                   const float2* __restrict__ tab) {
  __shared__ unsigned short Qs[64][72];
  __shared__ unsigned short KPs[320 * 72];   // K tile; later aliased as P[64][328]
  __shared__ unsigned short Vt[64][328];     // V^T, column-swizzled
  const int T = 2048;
  const int tid = threadIdx.x;
  const int bid = blockIdx.x;
  const int qt = bid & 31;
  const int bh = bid >> 5;
  const int b = bh >> 4, h = bh & 15;
  const int qbase = qt * 64;
  const int kbase = qbase - WMAX;
  const int win = *winp;
  const unsigned short* base = qkv + (size_t)b * T * 3072 + h * 192;
  const int tr = tid >> 2, tc = (tid & 3) * 16;
  const int vswz = (tid & 3) << 4;           // ((d>>4)&3)<<4 for d = tc..tc+15
  {  // stage Q (64x64) with RoPE
    const unsigned short* s = base + (size_t)(qbase + tr) * 3072 + tc;
    unsigned short tq[16];
    *(int4*)&tq[0] = *(const int4*)s;
    *(int4*)&tq[8] = *(const int4*)(s + 8);
    rope16(tq, tab + (qbase + tr) * 32 + tc / 2);
    *(int4*)&Qs[tr][tc]     = *(int4*)&tq[0];
    *(int4*)&Qs[tr][tc + 8] = *(int4*)&tq[8];
  }
#pragma unroll
  for (int p5 = 0; p5 < 5; ++p5) {  // stage K (RoPE) and V^T (swizzled)
    int s = p5 * 64 + tr;
    int j = kbase + s;
    int jc = j < 0 ? 0 : j;
    const unsigned short* sk = base + (size_t)jc * 3072 + 64 + tc;
    unsigned short tk[16];
    *(int4*)&tk[0] = *(const int4*)sk;
    *(int4*)&tk[8] = *(const int4*)(sk + 8);
    rope16(tk, tab + jc * 32 + tc / 2);
    *(int4*)&KPs[s * 72 + tc]     = *(int4*)&tk[0];
    *(int4*)&KPs[s * 72 + tc + 8] = *(int4*)&tk[8];
    const unsigned short* sv = base + (size_t)jc * 3072 + 128 + tc;
    unsigned short tmp[16];
    *(int4*)&tmp[0] = *(const int4*)sv;
    *(int4*)&tmp[8] = *(const int4*)(sv + 8);
    int ssw = s ^ vswz;
#pragma unroll
    for (int e = 0; e < 16; ++e) Vt[tc + e][ssw] = tmp[e];
  }
  __syncthreads();
  const int lane = tid & 63, wv = tid >> 6;
  const int rbase = wv * 16;
  const int rq = lane & 15, kg = (lane >> 4) * 8;
  bf16x8 qa[2];
#pragma unroll
  for (int kk = 0; kk < 2; ++kk)
    qa[kk] = *(const bf16x8*)&Qs[rbase + rq][kk * 32 + kg];
  float sc[20][4];
#pragma unroll
  for (int n = 0; n < 20; ++n) {
    // wave-uniform skip of fully-masked 16-column blocks
    int jlo = kbase + n * 16;
    if (jlo + 15 >= 0 && jlo <= qbase + rbase + 15) {
      f32x4 s = {};
#pragma unroll
      for (int kk = 0; kk < 2; ++kk) {
        bf16x8 kb = *(const bf16x8*)&KPs[(n * 16 + rq) * 72 + kk * 32 + kg];
        s = __builtin_amdgcn_mfma_f32_16x16x32_bf16(qa[kk], kb, s, 0, 0, 0);
      }
#pragma unroll
      for (int r = 0; r < 4; ++r) sc[n][r] = s[r];
    } else {
#pragma unroll
      for (int r = 0; r < 4; ++r) sc[n][r] = -1e30f;
    }
  }
  const float scale = 0.125f;  // 1/sqrt(64)
#pragma unroll
  for (int r = 0; r < 4; ++r) {
    const int i = qbase + rbase + (lane >> 4) * 4 + r;
    float mx = -1e30f;
#pragma unroll
    for (int n = 0; n < 20; ++n) {
      int j = kbase + n * 16 + rq;
      bool valid = (j >= 0) && (j <= i) && (i - j <= win);
      float v = valid ? sc[n][r] * scale : -1e30f;
      sc[n][r] = v;
      mx = fmaxf(mx, v);
    }
#pragma unroll
    for (int off = 1; off < 16; off <<= 1) mx = fmaxf(mx, __shfl_xor(mx, off));
    float sum = 0.f;
#pragma unroll
    for (int n = 0; n < 20; ++n) {
      float pv = __expf(sc[n][r] - mx);
      sc[n][r] = pv;
      sum += pv;
    }
#pragma unroll
    for (int off = 1; off < 16; off <<= 1) sum += __shfl_xor(sum, off);
    float inv = 1.0f / sum;
#pragma unroll
    for (int n = 0; n < 20; ++n) sc[n][r] *= inv;
  }
  __syncthreads();  // all K reads done before KPs is reused as P
#pragma unroll
  for (int n = 0; n < 20; ++n)
#pragma unroll
    for (int r = 0; r < 4; ++r)
      KPs[(rbase + (lane >> 4) * 4 + r) * 328 + n * 16 + rq] = f2bf(sc[n][r]);
  // PV: O(16x64) = P(16x320) * V(320x64), per wave; Vt reads un-swizzle
  f32x4 oacc[4] = {};
#pragma unroll
  for (int kk = 0; kk < 10; ++kk) {
    bf16x8 pa = *(const bf16x8*)&KPs[(rbase + rq) * 328 + kk * 32 + kg];
#pragma unroll
    for (int n = 0; n < 4; ++n) {
      bf16x8 vb = *(const bf16x8*)&Vt[n * 16 + rq][(kk * 32 + kg) ^ (n << 4)];
      oacc[n] = __builtin_amdgcn_mfma_f32_16x16x32_bf16(pa, vb, oacc[n], 0, 0, 0);
    }
  }
#pragma unroll
  for (int n = 0; n < 4; ++n)
#pragma unroll
    for (int j = 0; j < 4; ++j) {
      int r = qbase + rbase + (lane >> 4) * 4 + j;
      int d = n * 16 + rq;
      attnb[(size_t)(b * T + r) * 1024 + h * 64 + d] = f2bf(oacc[n][j]);
    }
}

// ---------------- launch ----------------------------------------------------
extern "C" void kernel_launch(void* const* d_in, const int* in_sizes, int n_in,
                              void* d_out, int out_size, void* d_ws, size_t ws_size,
                              hipStream_t stream) {
  const float* x    = (const float*)d_in[0];
  const float* Wqkv = (const float*)d_in[1];
  const float* Wout = (const float*)d_in[2];
  const int*   winp = (const int*)d_in[3];

  const int M = 4096, C = 1024, N1 = 3072;
  unsigned short* xb    = (unsigned short*)d_ws;
  unsigned short* wqkvb = xb    + (size_t)M * C;
  unsigned short* woutb = wqkvb + (size_t)N1 * C;
  unsigned short* qkvb  = woutb + (size_t)C * C;
  unsigned short* attnb = qkvb  + (size_t)M * N1;
  float2*         tab   = (float2*)(attnb + (size_t)M * C);  // 2048*32 float2

  const int PREP = 1048576 + 786432 + 262144 + 65536;
  prep_kernel<<<(PREP + 255) / 256, 256, 0, stream>>>(x, Wqkv, Wout, xb, wqkvb,
                                                      woutb, tab);

  gemm_bt<true><<<dim3(N1 / 128, M / 128), 256, 0, stream>>>(xb, wqkvb, qkvb,
                                                             M, N1, C);

  attn_kernel<<<2 * 16 * 32, 256, 0, stream>>>(qkvb, attnb, winp, tab);

  gemm_bt<false><<<dim3(C / 128, M / 128), 256, 0, stream>>>(attnb, woutb,
                                                             (float*)d_out, M, C, C);
}

// Round 10
// 187.879 us; speedup vs baseline: 1.2179x; 1.0322x over previous
//
#include <hip/hip_runtime.h>

typedef float f32x4 __attribute__((ext_vector_type(4)));
typedef __bf16 bf16x8 __attribute__((ext_vector_type(8)));
typedef unsigned short u16x4 __attribute__((ext_vector_type(4)));

__device__ __forceinline__ unsigned short f2bf(float f) {
  union { float f; unsigned int u; } v; v.f = f;
  unsigned int r = (v.u + 0x7FFFu + ((v.u >> 16) & 1u)) >> 16;
  return (unsigned short)r;
}
__device__ __forceinline__ float bf2f(unsigned short h) {
  union { unsigned int u; float f; } v; v.u = ((unsigned int)h) << 16;
  return v.f;
}
__device__ __forceinline__ void gload_lds16(const void* g, void* l) {
  __builtin_amdgcn_global_load_lds(
      (const __attribute__((address_space(1))) unsigned int*)g,
      (__attribute__((address_space(3))) unsigned int*)l, 16, 0, 0);
}

// ---------------- prep: fp32->bf16 casts (all 3 arrays) + RoPE cos/sin table
__global__ __launch_bounds__(256) void prep_kernel(
    const float* __restrict__ x, const float* __restrict__ wqkv,
    const float* __restrict__ wout, unsigned short* __restrict__ xb,
    unsigned short* __restrict__ wqkvb, unsigned short* __restrict__ woutb,
    float2* __restrict__ tab) {
  const int N1 = 1048576, N2 = 786432, N3 = 262144;  // float4 counts
  int idx = blockIdx.x * 256 + threadIdx.x;
  if (idx < N1 + N2 + N3) {
    const float* src; unsigned short* dst; int i = idx;
    if (i < N1)           { src = x;    dst = xb; }
    else if (i < N1 + N2) { i -= N1;      src = wqkv; dst = wqkvb; }
    else                  { i -= N1 + N2; src = wout; dst = woutb; }
    float4 v = ((const float4*)src)[i];
    u16x4 o;
    o.x = f2bf(v.x); o.y = f2bf(v.y); o.z = f2bf(v.z); o.w = f2bf(v.w);
    ((u16x4*)dst)[i] = o;
  } else {
    int i = idx - (N1 + N2 + N3);
    if (i < 65536) {  // 2048 positions x 32 pairs
      int t = i >> 5, p = i & 31;
      float theta = exp2f(-(float)p * 0.4152410118609203f);  // log2(1e4)/32
      float sn, cs;
      sincosf((float)t * theta, &sn, &cs);
      tab[i] = make_float2(cs, sn);
    }
  }
}

// ---------------- bf16 GEMM, C = A * B^T  (r3-measured 43.3us structure) ----
template <bool OUTBF16>
__global__ __launch_bounds__(256) void gemm_bt(const unsigned short* __restrict__ A,
                                               const unsigned short* __restrict__ B,
                                               void* __restrict__ C,
                                               int M, int N, int K) {
  __shared__ unsigned short As[128][32];
  __shared__ unsigned short Bs[128][32];
  const int tid = threadIdx.x;
  const int lane = tid & 63;
  const int w = tid >> 6, wr = w >> 1, wc = w & 1;
  const int bm = blockIdx.y * 128, bn = blockIdx.x * 128;
  const int t4 = tid >> 2, c8 = (tid & 3) * 8;
  const unsigned short* Ab = A + (size_t)(bm + t4) * K + c8;
  const unsigned short* Bb = B + (size_t)(bn + t4) * K + c8;
  const int rq = lane & 15, kg = (lane >> 4) * 8;
  f32x4 acc[4][4] = {};
  for (int kt = 0; kt < K; kt += 32) {
    gload_lds16(Ab + kt,                  &As[t4][c8]);
    gload_lds16(Ab + kt + (size_t)64 * K, &As[t4 + 64][c8]);
    gload_lds16(Bb + kt,                  &Bs[t4][c8]);
    gload_lds16(Bb + kt + (size_t)64 * K, &Bs[t4 + 64][c8]);
    __syncthreads();
    bf16x8 fa[4], fb[4];
#pragma unroll
    for (int m = 0; m < 4; ++m) fa[m] = *(const bf16x8*)&As[wr * 64 + m * 16 + rq][kg];
#pragma unroll
    for (int n = 0; n < 4; ++n) fb[n] = *(const bf16x8*)&Bs[wc * 64 + n * 16 + rq][kg];
#pragma unroll
    for (int m = 0; m < 4; ++m)
#pragma unroll
      for (int n = 0; n < 4; ++n)
        acc[m][n] = __builtin_amdgcn_mfma_f32_16x16x32_bf16(fa[m], fb[n], acc[m][n], 0, 0, 0);
    __syncthreads();
  }
  const int r0 = bm + wr * 64 + (lane >> 4) * 4;
  const int c0 = bn + wc * 64 + rq;
#pragma unroll
  for (int m = 0; m < 4; ++m)
#pragma unroll
    for (int n = 0; n < 4; ++n)
#pragma unroll
      for (int j = 0; j < 4; ++j) {
        int row = r0 + m * 16 + j, col = c0 + n * 16;
        if (OUTBF16)
          ((unsigned short*)C)[(size_t)row * N + col] = f2bf(acc[m][n][j]);
        else
          ((float*)C)[(size_t)row * N + col] = acc[m][n][j];
      }
}

// ---------------- RoPE in-place on q,k thirds of qkv (table-based) ---------
__global__ __launch_bounds__(256) void rope_inplace(unsigned short* __restrict__ qkv,
                                                    const float2* __restrict__ tab) {
  int idx = blockIdx.x * 256 + threadIdx.x;  // B*H*T*32 = 2M threads
  int dp = idx & 31;
  int t  = (idx >> 5) & 2047;
  int bh = idx >> 16;
  unsigned short* p = qkv + (size_t)((bh >> 4) * 2048 + t) * 3072 + (bh & 15) * 192 + dp * 2;
  float2 cs = tab[t * 32 + dp];
  float q1 = bf2f(p[0]), q2 = bf2f(p[1]);
  p[0] = f2bf(q1 * cs.x - q2 * cs.y);
  p[1] = f2bf(q1 * cs.y + q2 * cs.x);
  float k1 = bf2f(p[64]), k2 = bf2f(p[65]);
  p[64] = f2bf(k1 * cs.x - k2 * cs.y);
  p[65] = f2bf(k1 * cs.y + k2 * cs.x);
}

// ---------------- sliding-window attention, 80KB LDS (2 blocks/CU) ---------
// One 256-thread block per (b, h, 64-row q-tile). Key slots s=0..319 map to
// j = qbase-256+s (clamped to row 0 for staging; masked in scores).
// LDS (exactly 81920 B): Ks[320][64] block-swizzled (LDS[row][b]=G[row][b^(row&7)],
// staged via pre-swizzled global source + linear global_load_lds dest);
// Vt[64][320] with store map off(d,s)=d*320+((s^(((d>>4)&3)<<4))+d*8)%320;
// P aliases Ks after QK^T: off(q,c)=q*320+(c^((q&7)<<3)). Q is in registers.
#define WMAX 256
__global__ __launch_bounds__(256, 2) void attn_kernel(const unsigned short* __restrict__ qkv,
                                                      unsigned short* __restrict__ attnb,
                                                      const int* __restrict__ winp) {
  __shared__ unsigned short lds[40960];      // 81920 B total
  unsigned short* Ks = lds;                  // 20480 elems
  unsigned short* Vt = lds + 20480;          // 20480 elems
  const int T = 2048;
  const int tid = threadIdx.x;
  const int bid = blockIdx.x;
  const int qt = bid & 31;
  const int bh = bid >> 5;
  const int b = bh >> 4, h = bh & 15;
  const int qbase = qt * 64;
  const int kbase = qbase - WMAX;
  const int win = *winp;
  const unsigned short* base = qkv + (size_t)b * T * 3072 + h * 192;
  const int lane = tid & 63, wv = tid >> 6;
  const int rq = lane & 15, hi = lane >> 4, kg = hi * 8;
  const int rbase = wv * 16;
  // Q fragments straight from global (already RoPE'd)
  bf16x8 qa[2];
#pragma unroll
  for (int kk = 0; kk < 2; ++kk)
    qa[kk] = *(const bf16x8*)(base + (size_t)(qbase + rbase + rq) * 3072 + kk * 32 + kg);
  // K staging: 320 rows x 64, source-swizzled, async direct-to-LDS
#pragma unroll
  for (int it = 0; it < 10; ++it) {
    int ch = tid + it * 256;
    int row = ch >> 3, blk = ch & 7;
    int j = kbase + row;
    int jc = j < 0 ? 0 : j;
    gload_lds16(base + (size_t)jc * 3072 + 64 + ((blk ^ (row & 7)) * 8), Ks + ch * 8);
  }
  // V staging: register transpose into swizzled Vt
  {
    const int tr = tid >> 2, tc = (tid & 3) * 16;
    const int vsw = tc;  // (((d>>4)&3)<<4) for d in [tc, tc+16)
#pragma unroll
    for (int p5 = 0; p5 < 5; ++p5) {
      int s = p5 * 64 + tr;
      int j = kbase + s;
      int jc = j < 0 ? 0 : j;
      const unsigned short* sv = base + (size_t)jc * 3072 + 128 + tc;
      unsigned short tmp[16];
      *(int4*)&tmp[0] = *(const int4*)sv;
      *(int4*)&tmp[8] = *(const int4*)(sv + 8);
      int scol = s ^ vsw;
#pragma unroll
      for (int e = 0; e < 16; ++e) {
        int d = tc + e;
        int col = scol + d * 8;
        if (col >= 320) col -= 320;
        if (col >= 320) col -= 320;
        Vt[d * 320 + col] = tmp[e];
      }
    }
  }
  __syncthreads();
  // QK^T: scores 16x320 per wave (skip fully-invalid 16-col blocks)
  float sc[20][4];
#pragma unroll
  for (int n = 0; n < 20; ++n) {
    int jlo = kbase + n * 16;
    if (jlo + 15 >= 0 && jlo <= qbase + rbase + 15) {
      f32x4 s = {};
#pragma unroll
      for (int kk = 0; kk < 2; ++kk) {
        int row = n * 16 + rq;
        int blk = (hi + kk * 4) ^ (row & 7);
        bf16x8 kb = *(const bf16x8*)(Ks + row * 64 + blk * 8);
        s = __builtin_amdgcn_mfma_f32_16x16x32_bf16(qa[kk], kb, s, 0, 0, 0);
      }
#pragma unroll
      for (int r = 0; r < 4; ++r) sc[n][r] = s[r];
    } else {
#pragma unroll
      for (int r = 0; r < 4; ++r) sc[n][r] = -1e30f;
    }
  }
  // mask + softmax (rows in-register; reduce across 16 lanes)
  const float scale = 0.125f;  // 1/sqrt(64)
#pragma unroll
  for (int r = 0; r < 4; ++r) {
    const int i = qbase + rbase + hi * 4 + r;
    float mx = -1e30f;
#pragma unroll
    for (int n = 0; n < 20; ++n) {
      int j = kbase + n * 16 + rq;
      bool valid = (j >= 0) && (j <= i) && (i - j <= win);
      float v = valid ? sc[n][r] * scale : -1e30f;
      sc[n][r] = v;
      mx = fmaxf(mx, v);
    }
#pragma unroll
    for (int off = 1; off < 16; off <<= 1) mx = fmaxf(mx, __shfl_xor(mx, off));
    float sum = 0.f;
#pragma unroll
    for (int n = 0; n < 20; ++n) {
      float pv = __expf(sc[n][r] - mx);
      sc[n][r] = pv;
      sum += pv;
    }
#pragma unroll
    for (int off = 1; off < 16; off <<= 1) sum += __shfl_xor(sum, off);
    float inv = 1.0f / sum;
#pragma unroll
    for (int n = 0; n < 20; ++n) sc[n][r] *= inv;
  }
  __syncthreads();  // all waves' K reads done before Ks is reused as P
  // P into Ks alias: off(q,c) = q*320 + (c ^ ((q&7)<<3))
#pragma unroll
  for (int n = 0; n < 20; ++n)
#pragma unroll
    for (int r = 0; r < 4; ++r) {
      int q = rbase + hi * 4 + r;
      int c = (n * 16 + rq) ^ ((q & 7) << 3);
      Ks[q * 320 + c] = f2bf(sc[n][r]);
    }
  // PV: O(16x64) = P(16x320) * Vt(64x320)^T per wave (own rows only)
  f32x4 oacc[4] = {};
#pragma unroll
  for (int kk = 0; kk < 10; ++kk) {
    int prow = rbase + rq;
    int pc = (kk * 32 + kg) ^ ((rq & 7) << 3);
    bf16x8 pa = *(const bf16x8*)(Ks + prow * 320 + pc);
#pragma unroll
    for (int n = 0; n < 4; ++n) {
      int d = n * 16 + rq;
      int scol = (kk * 32 + kg) ^ ((n & 3) << 4);
      int col = scol + d * 8;
      if (col >= 320) col -= 320;
      if (col >= 320) col -= 320;
      bf16x8 vb = *(const bf16x8*)(Vt + d * 320 + col);
      oacc[n] = __builtin_amdgcn_mfma_f32_16x16x32_bf16(pa, vb, oacc[n], 0, 0, 0);
    }
  }
#pragma unroll
  for (int n = 0; n < 4; ++n)
#pragma unroll
    for (int j = 0; j < 4; ++j) {
      int r = qbase + rbase + hi * 4 + j;
      int d = n * 16 + rq;
      attnb[(size_t)(b * T + r) * 1024 + h * 64 + d] = f2bf(oacc[n][j]);
    }
}

// ---------------- launch ----------------------------------------------------
extern "C" void kernel_launch(void* const* d_in, const int* in_sizes, int n_in,
                              void* d_out, int out_size, void* d_ws, size_t ws_size,
                              hipStream_t stream) {
  const float* x    = (const float*)d_in[0];
  const float* Wqkv = (const float*)d_in[1];
  const float* Wout = (const float*)d_in[2];
  const int*   winp = (const int*)d_in[3];

  const int M = 4096, C = 1024, N1 = 3072;
  unsigned short* xb    = (unsigned short*)d_ws;
  unsigned short* wqkvb = xb    + (size_t)M * C;
  unsigned short* woutb = wqkvb + (size_t)N1 * C;
  unsigned short* qkvb  = woutb + (size_t)C * C;
  unsigned short* attnb = qkvb  + (size_t)M * N1;
  float2*         tab   = (float2*)(attnb + (size_t)M * C);  // 2048*32 float2

  const int PREP = 1048576 + 786432 + 262144 + 65536;
  prep_kernel<<<(PREP + 255) / 256, 256, 0, stream>>>(x, Wqkv, Wout, xb, wqkvb,
                                                      woutb, tab);

  gemm_bt<true><<<dim3(N1 / 128, M / 128), 256, 0, stream>>>(xb, wqkvb, qkvb,
                                                             M, N1, C);

  rope_inplace<<<(2 * 16 * 2048 * 32) / 256, 256, 0, stream>>>(qkvb, tab);

  attn_kernel<<<2 * 16 * 32, 256, 0, stream>>>(qkvb, attnb, winp);

  gemm_bt<false><<<dim3(C / 128, M / 128), 256, 0, stream>>>(attnb, woutb,
                                                             (float*)d_out, M, C, C);
}